// Round 2
// baseline (39.121 us; speedup 1.0000x reference)
//
#include <hip/hip_runtime.h>

// SmoothnessLoss: mean over [B,4,H,W] of smooth_l1(stencil(in - tgt)) * mask
// B=16, C=1, H=W=1024, fp32 in/out. Output: single fp32 scalar.
//
// Stencils on d = in - tgt (linear conv => grads(in)-grads(tgt) = grads(d)):
//   fx  = d(y,x-1) - 2 d(y,x) + d(y,x+1)        mask: zero at x==W-1
//   fy  = d(y-1,x) - 2 d(y,x) + d(y+1,x)        mask: zero at y==H-1
//   fd1 = d(y-1,x-1) - 2 d(y,x) + d(y+1,x+1)    mask: zero on all borders
//   fd2 = d(y-1,x+1) - 2 d(y,x) + d(y+1,x-1)    mask: zero on all borders
//
// R1 change: latency-bound (replays run at same speed with FETCH~0 => L3-
// resident, not HBM-bound; VALUBusy 25%). Issue ALL strip loads up-front
// (10 rows x 6 loads in flight per wave) instead of 1 row/iteration.

#define BB 16
#define HH 1024
#define WW 1024
#define RR 8   // rows per block-strip; load volume = (RR+2)/RR x ideal

__device__ __forceinline__ float sl1(float v) {
  // smooth_l1, branchless: ad<1 -> 0.5 ad^2 ; else ad-0.5
  float ad = fabsf(v);
  float t = fminf(ad, 1.0f);
  return fmaf(0.5f * t, t, ad - t);
}

__global__ __launch_bounds__(256) void smooth_partial(
    const float* __restrict__ in, const float* __restrict__ tg,
    float* __restrict__ ws) {
  const int tid = threadIdx.x;
  const int x0  = tid * 4;                  // 256 threads x 4 cols = W
  const int strip = blockIdx.x;             // 0 .. B*(H/RR)-1
  const int bi = strip >> 7;                // / (HH/RR) = / 128
  const int r0 = (strip & 127) * RR;
  const int imgBase = bi * (HH * WW);

  // ---- phase 1: issue ALL loads for the strip (rows r0-1 .. r0+RR) ----
  float4 ac[RR + 2], bc[RR + 2];
  float  al[RR + 2], ar[RR + 2], bl[RR + 2], br[RR + 2];

  #pragma unroll
  for (int k = 0; k < RR + 2; ++k) {
    const int y = r0 - 1 + k;
    if (y >= 0 && y < HH) {                 // wave-uniform branch
      const int base = imgBase + y * WW + x0;
      ac[k] = *reinterpret_cast<const float4*>(in + base);
      bc[k] = *reinterpret_cast<const float4*>(tg + base);
      al[k] = (x0 > 0)      ? in[base - 1] : 0.f;
      bl[k] = (x0 > 0)      ? tg[base - 1] : 0.f;
      ar[k] = (x0 + 4 < WW) ? in[base + 4] : 0.f;
      br[k] = (x0 + 4 < WW) ? tg[base + 4] : 0.f;
    } else {
      ac[k] = make_float4(0.f, 0.f, 0.f, 0.f);
      bc[k] = make_float4(0.f, 0.f, 0.f, 0.f);
      al[k] = ar[k] = bl[k] = br[k] = 0.f;
    }
  }

  // ---- phase 2: difference rows (raw regs die progressively) ----
  float D[RR + 2][6];   // all indices compile-time after unroll -> registers
  #pragma unroll
  for (int k = 0; k < RR + 2; ++k) {
    D[k][0] = al[k] - bl[k];
    D[k][1] = ac[k].x - bc[k].x;
    D[k][2] = ac[k].y - bc[k].y;
    D[k][3] = ac[k].z - bc[k].z;
    D[k][4] = ac[k].w - bc[k].w;
    D[k][5] = ar[k] - br[k];
  }

  // ---- phase 3: stencils + smooth-L1 + masks ----
  float sum = 0.f;
  #pragma unroll
  for (int k = 0; k < RR; ++k) {
    const int y = r0 + k;
    const float my  = (y == HH - 1) ? 0.f : 1.f;
    const float mdy = (y == 0 || y == HH - 1) ? 0.f : 1.f;
    #pragma unroll
    for (int j = 1; j <= 4; ++j) {
      const int x = x0 + j - 1;
      const float c2 = -2.f * D[k+1][j];
      const float fx = (D[k+1][j-1] + D[k+1][j+1]) + c2;
      const float fy = (D[k  ][j  ] + D[k+2][j  ]) + c2;
      const float f1 = (D[k  ][j-1] + D[k+2][j+1]) + c2;
      const float f2 = (D[k  ][j+1] + D[k+2][j-1]) + c2;
      const float mx  = (x == WW - 1) ? 0.f : 1.f;
      const float mdx = (x == 0 || x == WW - 1) ? 0.f : 1.f;
      sum += sl1(fx) * mx + sl1(fy) * my + (sl1(f1) + sl1(f2)) * (mdx * mdy);
    }
  }

  // ---- deterministic block reduction ----
  for (int off = 32; off > 0; off >>= 1) sum += __shfl_down(sum, off, 64);
  __shared__ float sh[4];
  const int wave = tid >> 6, lane = tid & 63;
  if (lane == 0) sh[wave] = sum;
  __syncthreads();
  if (tid == 0) ws[blockIdx.x] = (sh[0] + sh[1]) + (sh[2] + sh[3]);
}

__global__ __launch_bounds__(256) void smooth_final(
    const float* __restrict__ ws, float* __restrict__ out, int n) {
  float s = 0.f;
  for (int i = threadIdx.x; i < n; i += 256) s += ws[i];
  for (int off = 32; off > 0; off >>= 1) s += __shfl_down(s, off, 64);
  __shared__ float sh[4];
  const int wave = threadIdx.x >> 6, lane = threadIdx.x & 63;
  if (lane == 0) sh[wave] = s;
  __syncthreads();
  if (threadIdx.x == 0) {
    const float scale = 1.0f / (float)((long long)BB * 4LL * HH * WW);
    out[0] = ((sh[0] + sh[1]) + (sh[2] + sh[3])) * scale;
  }
}

extern "C" void kernel_launch(void* const* d_in, const int* in_sizes, int n_in,
                              void* d_out, int out_size, void* d_ws, size_t ws_size,
                              hipStream_t stream) {
  const float* in = (const float*)d_in[0];
  const float* tg = (const float*)d_in[1];
  float* out = (float*)d_out;
  float* ws  = (float*)d_ws;   // B*(H/RR)*4 = 8 KiB, well under ws_size

  const int nblocks = BB * (HH / RR);  // 2048 blocks, 256 threads each
  smooth_partial<<<nblocks, 256, 0, stream>>>(in, tg, ws);
  smooth_final<<<1, 256, 0, stream>>>(ws, out, nblocks);
}

// Round 3
// 36.933 us; speedup vs baseline: 1.0592x; 1.0592x over previous
//
#include <hip/hip_runtime.h>

// SmoothnessLoss: mean over [B,4,H,W] of smooth_l1(stencil(in - tgt)) * mask
// B=16, C=1, H=W=1024, fp32 in/out. Output: single fp32 scalar.
//
// Stencils on d = in - tgt (conv is linear => grads(in)-grads(tgt)=grads(d)):
//   fx  = d(y,x-1) - 2 d(y,x) + d(y,x+1)        mask: zero at x==W-1
//   fy  = d(y-1,x) - 2 d(y,x) + d(y+1,x)        mask: zero at y==H-1
//   fd1 = d(y-1,x-1) - 2 d(y,x) + d(y+1,x+1)    mask: zero on all borders
//   fd2 = d(y-1,x+1) - 2 d(y,x) + d(y+1,x-1)    mask: zero on all borders
//
// R3: kill the 40 scalar halo loads/wave (2/3 of all L1 line-requests, all
// redundant with neighbor vec-load lines). Halos now come from __shfl of the
// computed diff; the 3 intra-block wave boundaries go through 320B of LDS.
// sched_barrier(0) pins all 20 vec loads ahead of any consumer.

#define BB 16
#define HH 1024
#define WW 1024
#define RR 8   // rows per block-strip; load volume = (RR+2)/RR x ideal

__device__ __forceinline__ float sl1(float v) {
  float ad = fabsf(v);
  float t = fminf(ad, 1.0f);
  return fmaf(0.5f * t, t, ad - t);   // ad<1 ? 0.5 ad^2 : ad-0.5
}

__global__ __launch_bounds__(256) void smooth_partial(
    const float* __restrict__ in, const float* __restrict__ tg,
    float* __restrict__ ws) {
  const int tid  = threadIdx.x;
  const int lane = tid & 63;
  const int wave = tid >> 6;
  const int x0   = tid * 4;                 // 256 threads x 4 cols = W
  const int strip = blockIdx.x;             // 0 .. B*(H/RR)-1
  const int bi = strip >> 7;                // / (HH/RR) = /128
  const int r0 = (strip & 127) * RR;
  const int imgBase = bi * (HH * WW);

  // ---- phase 1: issue ALL vec loads for the strip (rows r0-1 .. r0+RR) ----
  float4 a4[RR + 2], b4[RR + 2];
  #pragma unroll
  for (int k = 0; k < RR + 2; ++k) {
    const int y = r0 - 1 + k;
    if (y >= 0 && y < HH) {                 // wave-uniform branch
      const int base = imgBase + y * WW + x0;
      a4[k] = *reinterpret_cast<const float4*>(in + base);
      b4[k] = *reinterpret_cast<const float4*>(tg + base);
    } else {
      a4[k] = make_float4(0.f, 0.f, 0.f, 0.f);
      b4[k] = make_float4(0.f, 0.f, 0.f, 0.f);
    }
  }
  __builtin_amdgcn_sched_barrier(0);  // keep all 20 loads issued up-front

  // ---- phase 2: diffs + halos via shuffle (no halo memory traffic) ----
  float4 Dc[RR + 2];
  float  Dl[RR + 2], Dr[RR + 2];
  __shared__ float shL[4][RR + 2];   // lane63's Dc.w per wave
  __shared__ float shR[4][RR + 2];   // lane0's  Dc.x per wave

  #pragma unroll
  for (int k = 0; k < RR + 2; ++k) {
    Dc[k].x = a4[k].x - b4[k].x;
    Dc[k].y = a4[k].y - b4[k].y;
    Dc[k].z = a4[k].z - b4[k].z;
    Dc[k].w = a4[k].w - b4[k].w;
    Dl[k] = __shfl_up(Dc[k].w, 1, 64);     // lane-1's .w  (lane 0: fixed below)
    Dr[k] = __shfl_down(Dc[k].x, 1, 64);   // lane+1's .x  (lane 63: fixed below)
    if (lane == 63) shL[wave][k] = Dc[k].w;
    if (lane == 0)  shR[wave][k] = Dc[k].x;
  }
  __syncthreads();
  #pragma unroll
  for (int k = 0; k < RR + 2; ++k) {
    if (lane == 0)  Dl[k] = (wave > 0) ? shL[wave - 1][k] : 0.f;  // x0==0: zero pad
    if (lane == 63) Dr[k] = (wave < 3) ? shR[wave + 1][k] : 0.f;  // x==1023: zero pad
  }

  // ---- phase 3: stencils + smooth-L1 + masks ----
  float sum = 0.f;
  #pragma unroll
  for (int k = 0; k < RR; ++k) {
    const int y = r0 + k;
    const float my  = (y == HH - 1) ? 0.f : 1.f;
    const float mdy = (y == 0 || y == HH - 1) ? 0.f : 1.f;
    const float P[6] = {Dl[k  ], Dc[k  ].x, Dc[k  ].y, Dc[k  ].z, Dc[k  ].w, Dr[k  ]};
    const float C[6] = {Dl[k+1], Dc[k+1].x, Dc[k+1].y, Dc[k+1].z, Dc[k+1].w, Dr[k+1]};
    const float N[6] = {Dl[k+2], Dc[k+2].x, Dc[k+2].y, Dc[k+2].z, Dc[k+2].w, Dr[k+2]};
    #pragma unroll
    for (int j = 1; j <= 4; ++j) {
      const int x = x0 + j - 1;
      const float c2 = -2.f * C[j];
      const float fx = (C[j-1] + C[j+1]) + c2;
      const float fy = (P[j]   + N[j]  ) + c2;
      const float f1 = (P[j-1] + N[j+1]) + c2;
      const float f2 = (P[j+1] + N[j-1]) + c2;
      const float mx  = (x == WW - 1) ? 0.f : 1.f;
      const float mdx = (x == 0 || x == WW - 1) ? 0.f : 1.f;
      sum += sl1(fx) * mx + sl1(fy) * my + (sl1(f1) + sl1(f2)) * (mdx * mdy);
    }
  }

  // ---- deterministic block reduction ----
  for (int off = 32; off > 0; off >>= 1) sum += __shfl_down(sum, off, 64);
  __shared__ float sh[4];
  if (lane == 0) sh[wave] = sum;
  __syncthreads();
  if (tid == 0) ws[blockIdx.x] = (sh[0] + sh[1]) + (sh[2] + sh[3]);
}

__global__ __launch_bounds__(256) void smooth_final(
    const float* __restrict__ ws, float* __restrict__ out, int n) {
  float s = 0.f;
  for (int i = threadIdx.x; i < n; i += 256) s += ws[i];
  for (int off = 32; off > 0; off >>= 1) s += __shfl_down(s, off, 64);
  __shared__ float sh[4];
  const int wave = threadIdx.x >> 6, lane = threadIdx.x & 63;
  if (lane == 0) sh[wave] = s;
  __syncthreads();
  if (threadIdx.x == 0) {
    const float scale = 1.0f / (float)((long long)BB * 4LL * HH * WW);
    out[0] = ((sh[0] + sh[1]) + (sh[2] + sh[3])) * scale;
  }
}

extern "C" void kernel_launch(void* const* d_in, const int* in_sizes, int n_in,
                              void* d_out, int out_size, void* d_ws, size_t ws_size,
                              hipStream_t stream) {
  const float* in = (const float*)d_in[0];
  const float* tg = (const float*)d_in[1];
  float* out = (float*)d_out;
  float* ws  = (float*)d_ws;   // B*(H/RR)*4 = 8 KiB, well under ws_size

  const int nblocks = BB * (HH / RR);  // 2048 blocks, 256 threads each
  smooth_partial<<<nblocks, 256, 0, stream>>>(in, tg, ws);
  smooth_final<<<1, 256, 0, stream>>>(ws, out, nblocks);
}